// Round 2
// baseline (292.412 us; speedup 1.0000x reference)
//
#include <hip/hip_runtime.h>
#include <hip/hip_bf16.h>
#include <math.h>

// Problem constants
#define BATCH 64
#define SEQ   512
#define DIM   768
#define NW    256              // MAX_WORDS
#define NT    (BATCH * NW)     // 16384 tokens
#define KDIM  1536             // 2*DIM
#define HID   256              // router hidden
#define NL    7                // num labels

// GEMM tiling
#define BM  32
#define BK  64
#define BKP 72                 // padded LDS row stride (bf16) -> 144 B
#define NKT (KDIM / BK)        // 24

typedef __bf16 bf16_t;
typedef bf16_t bf16x4 __attribute__((ext_vector_type(4)));
typedef bf16_t bf16x8 __attribute__((ext_vector_type(8)));
typedef float  f32x4  __attribute__((ext_vector_type(4)));

// ---------------------------------------------------------------------------
// Kernel 1 (fused): convert router_w1 -> bf16 K-major tiles  AND  build the
// starts table. blocks 0..191 = w1 convert; blocks 192..319 = starts.
// ---------------------------------------------------------------------------
__global__ __launch_bounds__(256) void prep_kernel(
    const float* __restrict__ w1, bf16_t* __restrict__ w1t,
    const int* __restrict__ idh, const int* __restrict__ idr,
    int* __restrict__ starts)
{
    if (blockIdx.x < 192) {
        int kc = blockIdx.x >> 3;        // 0..23
        int kg = blockIdx.x & 7;         // 0..7
        int n  = threadIdx.x;            // 0..255
        bf16x8 v;
        #pragma unroll
        for (int j = 0; j < 8; j++)
            v[j] = (bf16_t)w1[(size_t)(kc * 64 + kg * 8 + j) * HID + n];
        *(bf16x8*)(w1t + (size_t)kc * (HID * BK) + n * BK + kg * 8) = v;
    } else {
        int blk = blockIdx.x - 192;      // 0..127 = 2 tensors x 64 batches
        int t = blk >> 6;
        int b = blk & 63;
        const int* ids = (t ? idr : idh) + b * SEQ;
        int w = threadIdx.x;
        int lo = 0, hi = SEQ;
        while (lo < hi) {
            int m = (lo + hi) >> 1;
            if (ids[m] < w) lo = m + 1; else hi = m;
        }
        int* row = starts + blk * 257;
        row[w] = lo;
        if (w == 0) row[256] = SEQ;
    }
}

// ---------------------------------------------------------------------------
// Kernel 2: segment-mean align — LDS-DMA streaming version.
//
// R1 post-mortem: two attempts at register double-buffering were flattened
// by the register allocator (VGPR_Count=48 both times; loads sunk into the
// drain's control flow and serialized -> 5-8% VALUBusy, 95 us).  The fix:
// hold in-flight load state in the LDS-DMA queue via
// __builtin_amdgcn_global_load_lds (no destination VGPRs -> the allocator
// has nothing to serialize), and get latency hiding from TLP: 32 KB
// LDS/block -> 5 blocks/CU = 20 resident waves/CU, each with an 8 KB chunk
// in flight (160 KB/CU >> the ~10 KB needed to saturate HBM).
//
// Wave-task = (b, tensor, 16-word block, 256-float col chunk): 6144 tasks,
// grid 1536 x 256 (4 waves/block, each wave owns an 8 KB LDS quadrant,
// no __syncthreads anywhere).  Each wave walks its contiguous subtoken row
// range [st[0], st[WPT]) exactly once in 8-row chunks:
//   issue 8x global_load_lds (1 KB/row: 64 lanes x 16 B)  -> vmcnt(0)
//   -> ds_read_b128 + accumulate + wave-uniform boundary emits.
// ---------------------------------------------------------------------------
#define WPT 16                 // words per task
#define CH  8                  // rows per LDS chunk (8 KB per wave)

typedef const __attribute__((address_space(1))) uint32_t g_u32;
typedef __attribute__((address_space(3))) uint32_t lds_u32;

__device__ __forceinline__ void gload_lds16(const float* g, float* l) {
    // HW semantics: per-lane global source address; LDS dest = wave-uniform
    // base + lane*16.  Our layout matches: lane i's 16 B row slice lands at
    // row_base + i*16.
    __builtin_amdgcn_global_load_lds((g_u32*)g, (lds_u32*)l, 16, 0, 0);
}

__global__ __launch_bounds__(256, 2) void align_kernel(
    const float* __restrict__ hh, const float* __restrict__ hr,
    const int* __restrict__ starts, bf16_t* __restrict__ X)
{
    __shared__ float lds[4][CH][256];    // 32 KB: one [CH][256] slab per wave

    int tid  = threadIdx.x;
    int lane = tid & 63;
    int wv   = tid >> 6;
    int task = blockIdx.x * 4 + wv;      // 0..6143
    int dc   = task % 3;                 // col chunk: floats [dc*256, dc*256+256)
    int q    = task / 3;                 // 0..2047
    int wb   = q & 15;                   // 16-word block index
    int t    = (q >> 4) & 1;
    int b    = q >> 5;

    const int*   st  = starts + (t * 64 + b) * 257 + wb * WPT;   // st[0..WPT]
    const float* src = (t ? hr : hh) + (size_t)b * SEQ * DIM + dc * 256;
    bf16_t*      dst = X + (size_t)b * NW * KDIM + (size_t)wb * WPT * KDIM
                         + t * DIM + dc * 256;
    float*       myl = &lds[wv][0][0];

    bf16x4 zero4 = {};
    int lo = st[0];
    int hi = st[WPT];

    int w  = 0;
    int nb = st[1];
    // leading (and possibly all) empty words: boundary == lo
    while (nb == lo) {
        *(bf16x4*)(dst + (size_t)w * KDIM + lane * 4) = zero4;
        w++;
        if (w == WPT) break;
        nb = st[w + 1];
    }

    if (lo < hi) {
        f32x4 acc = {0.f, 0.f, 0.f, 0.f};
        int wstart = lo;                 // == st[w] after the empty sweep

        for (int cs = lo; cs < hi; cs += CH) {
            // ---- issue CH row loads into this wave's LDS slab (clamped
            // duplicates for the tail chunk: harmless, skipped in drain) ----
            #pragma unroll
            for (int i = 0; i < CH; i++) {
                int s = cs + i;
                s = s < hi ? s : hi - 1;
                gload_lds16(src + (size_t)s * DIM + lane * 4, myl + i * 256);
            }
            asm volatile("s_waitcnt vmcnt(0)" ::: "memory");

            // ---- drain: accumulate + wave-uniform boundary emits ----
            #pragma unroll
            for (int i = 0; i < CH; i++) {
                int s = cs + i;
                if (s < hi) {
                    f32x4 v = *(const f32x4*)(myl + i * 256 + lane * 4);
                    acc[0] += v[0]; acc[1] += v[1];
                    acc[2] += v[2]; acc[3] += v[3];
                    if (s + 1 == nb) {           // word w complete
                        float invn = 1.0f / (float)(nb - wstart);
                        bf16x4 o;
                        o[0] = (bf16_t)(acc[0] * invn);
                        o[1] = (bf16_t)(acc[1] * invn);
                        o[2] = (bf16_t)(acc[2] * invn);
                        o[3] = (bf16_t)(acc[3] * invn);
                        *(bf16x4*)(dst + (size_t)w * KDIM + lane * 4) = o;
                        acc = (f32x4){0.f, 0.f, 0.f, 0.f};
                        w++; wstart = nb;
                        while (w < WPT) {        // emit empty words
                            int nb2 = st[w + 1];
                            if (nb2 > wstart) { nb = nb2; break; }
                            *(bf16x4*)(dst + (size_t)w * KDIM + lane * 4) = zero4;
                            w++;
                        }
                    }
                }
            }
        }
    }
}

// ---------------------------------------------------------------------------
// Kernel 3: router GEMM (bf16 MFMA) via LDS -> alpha.  (unchanged)
// ---------------------------------------------------------------------------
__global__ __launch_bounds__(256) void gemm_alpha_kernel(
    const bf16_t* __restrict__ X, const bf16_t* __restrict__ w1t,
    const float* __restrict__ b1, const float* __restrict__ w2,
    const float* __restrict__ b2, float* __restrict__ out)
{
    __shared__ __align__(16) bf16_t Xs[BM][BKP];
    __shared__ __align__(16) bf16_t Ws[HID][BKP];
    __shared__ float alpha_acc[BM];

    int tid   = threadIdx.x;
    int lane  = tid & 63;
    int wv    = tid >> 6;
    int row16 = lane & 15;
    int quad  = lane >> 4;
    int tok0  = blockIdx.x * BM;

    f32x4 acc[2][4];
    #pragma unroll
    for (int mi = 0; mi < 2; mi++)
        #pragma unroll
        for (int ni = 0; ni < 4; ni++)
            acc[mi][ni] = (f32x4){0.f, 0.f, 0.f, 0.f};

    int xr = tid >> 3;
    int xc = tid & 7;

    for (int kc = 0; kc < NKT; kc++) {
        {
            const uint4* src = (const uint4*)(X + (size_t)(tok0 + xr) * KDIM + kc * BK + xc * 8);
            *(uint4*)(&Xs[xr][xc * 8]) = *src;
        }
        {
            const uint4* srcb = (const uint4*)(w1t + (size_t)kc * (HID * BK));
            #pragma unroll
            for (int i = 0; i < 8; i++) {
                int cidx = tid + i * 256;
                *(uint4*)(&Ws[cidx >> 3][(cidx & 7) * 8]) = srcb[cidx];
            }
        }
        __syncthreads();
        #pragma unroll
        for (int kk2 = 0; kk2 < 2; kk2++) {
            bf16x8 af[2], bfg[4];
            #pragma unroll
            for (int mi = 0; mi < 2; mi++)
                af[mi] = *(const bf16x8*)(&Xs[mi * 16 + row16][kk2 * 32 + quad * 8]);
            #pragma unroll
            for (int ni = 0; ni < 4; ni++)
                bfg[ni] = *(const bf16x8*)(&Ws[wv * 64 + ni * 16 + row16][kk2 * 32 + quad * 8]);
            #pragma unroll
            for (int mi = 0; mi < 2; mi++)
                #pragma unroll
                for (int ni = 0; ni < 4; ni++)
                    acc[mi][ni] = __builtin_amdgcn_mfma_f32_16x16x32_bf16(
                        af[mi], bfg[ni], acc[mi][ni], 0, 0, 0);
        }
        __syncthreads();
    }

    float w2v[4], b1v[4];
    #pragma unroll
    for (int ni = 0; ni < 4; ni++) {
        int col = wv * 64 + ni * 16 + row16;
        w2v[ni] = w2[col];
        b1v[ni] = b1[col];
    }
    if (tid < BM) alpha_acc[tid] = 0.f;
    __syncthreads();

    #pragma unroll
    for (int mi = 0; mi < 2; mi++) {
        #pragma unroll
        for (int r = 0; r < 4; r++) {
            float p = 0.f;
            #pragma unroll
            for (int ni = 0; ni < 4; ni++) {
                float v = acc[mi][ni][r] + b1v[ni];
                v = v > 0.f ? v : 0.f;
                p += v * w2v[ni];
            }
            p += __shfl_xor(p, 1);
            p += __shfl_xor(p, 2);
            p += __shfl_xor(p, 4);
            p += __shfl_xor(p, 8);
            if (row16 == 0)
                atomicAdd(&alpha_acc[mi * 16 + quad * 4 + r], p);
        }
    }
    __syncthreads();
    if (tid < BM) {
        float a = 1.f / (1.f + expf(-(alpha_acc[tid] + b2[0])));
        out[(size_t)NT * NL + tok0 + tid] = a;
    }
}

// ---------------------------------------------------------------------------
// Kernel 4: blend + head + l2. 8 tokens per wave. Grid 512. (unchanged)
// ---------------------------------------------------------------------------
__global__ __launch_bounds__(256) void blend_kernel(
    const bf16_t* __restrict__ X, const float* __restrict__ hw,
    const float* __restrict__ hb, float* __restrict__ out)
{
    __shared__ float hws[NL * DIM];       // [l][d]
    int tid  = threadIdx.x;
    int lane = tid & 63;
    int wv   = tid >> 6;

    for (int i = tid; i < DIM * NL; i += 256) {
        int d = i / NL, l = i - d * NL;
        hws[l * DIM + d] = hw[i];
    }
    __syncthreads();

    int g   = lane >> 3;
    int u   = lane & 7;
    int tok = blockIdx.x * 32 + wv * 8 + g;

    float a = out[(size_t)NT * NL + tok];
    const bf16_t* xrow = X + (size_t)tok * KDIM;

    float lg[NL] = {0.f, 0.f, 0.f, 0.f, 0.f, 0.f, 0.f};
    float l2 = 0.f;

    #pragma unroll
    for (int k = 0; k < 12; k++) {
        int d0 = (k * 8 + u) * 8;
        bf16x8 hp = *(const bf16x8*)(xrow + d0);
        bf16x8 rp = *(const bf16x8*)(xrow + DIM + d0);
        float bl[8];
        #pragma unroll
        for (int e = 0; e < 8; e++) {
            float hhv = (float)hp[e];
            float hrv = (float)rp[e];
            float df  = hhv - hrv;
            bl[e] = fmaf(a, df, hrv);
            l2 = fmaf(df, df, l2);
        }
        #pragma unroll
        for (int l = 0; l < NL; l++) {
            f32x4 wA = *(const f32x4*)(&hws[l * DIM + d0]);
            f32x4 wB = *(const f32x4*)(&hws[l * DIM + d0 + 4]);
            lg[l] += bl[0]*wA[0] + bl[1]*wA[1] + bl[2]*wA[2] + bl[3]*wA[3]
                   + bl[4]*wB[0] + bl[5]*wB[1] + bl[6]*wB[2] + bl[7]*wB[3];
        }
    }

    #pragma unroll
    for (int off = 1; off < 8; off <<= 1) {
        #pragma unroll
        for (int l = 0; l < NL; l++) lg[l] += __shfl_xor(lg[l], off);
        l2 += __shfl_xor(l2, off);
    }

    if (u < NL) {
        float v = (u == 0) ? lg[0] : (u == 1) ? lg[1] : (u == 2) ? lg[2]
                : (u == 3) ? lg[3] : (u == 4) ? lg[4] : (u == 5) ? lg[5] : lg[6];
        out[(size_t)tok * NL + u] = v + hb[u];
    } else {
        out[(size_t)NT * NL + NT + tok] = sqrtf(l2);
    }
}

// ---------------------------------------------------------------------------
extern "C" void kernel_launch(void* const* d_in, const int* in_sizes, int n_in,
                              void* d_out, int out_size, void* d_ws, size_t ws_size,
                              hipStream_t stream)
{
    const float* hh  = (const float*)d_in[0];
    const float* hr  = (const float*)d_in[1];
    const int*   idh = (const int*)d_in[2];
    const int*   idr = (const int*)d_in[3];
    const float* w1  = (const float*)d_in[5];
    const float* b1  = (const float*)d_in[6];
    const float* w2  = (const float*)d_in[7];
    const float* b2  = (const float*)d_in[8];
    const float* hw  = (const float*)d_in[9];
    const float* hb  = (const float*)d_in[10];
    float* out = (float*)d_out;

    bf16_t* X      = (bf16_t*)d_ws;                        // 50.33 MB
    bf16_t* w1t    = X + (size_t)NT * KDIM;                // 0.79 MB (tiled)
    int*    starts = (int*)(w1t + (size_t)NKT * HID * BK); // 263 KB

    prep_kernel<<<320, 256, 0, stream>>>(w1, w1t, idh, idr, starts);
    align_kernel<<<1536, 256, 0, stream>>>(hh, hr, starts, X);
    gemm_alpha_kernel<<<NT / BM, 256, 0, stream>>>(X, w1t, b1, w2, b2, out);
    blend_kernel<<<512, 256, 0, stream>>>(X, hw, hb, out);
}

// Round 3
// 279.834 us; speedup vs baseline: 1.0449x; 1.0449x over previous
//
#include <hip/hip_runtime.h>
#include <hip/hip_bf16.h>
#include <math.h>

// Problem constants
#define BATCH 64
#define SEQ   512
#define DIM   768
#define NW    256              // MAX_WORDS
#define NT    (BATCH * NW)     // 16384 tokens
#define KDIM  1536             // 2*DIM
#define HID   256              // router hidden
#define NL    7                // num labels

// GEMM tiling
#define BM  32
#define BK  64
#define BKP 72                 // padded LDS row stride (bf16) -> 144 B
#define NKT (KDIM / BK)        // 24

typedef __bf16 bf16_t;
typedef bf16_t bf16x4 __attribute__((ext_vector_type(4)));
typedef bf16_t bf16x8 __attribute__((ext_vector_type(8)));
typedef float  f32x4  __attribute__((ext_vector_type(4)));

// ---------------------------------------------------------------------------
// Kernel 1 (fused): convert router_w1 -> bf16 K-major tiles  AND  build the
// starts table. blocks 0..191 = w1 convert; blocks 192..319 = starts.
// ---------------------------------------------------------------------------
__global__ __launch_bounds__(256) void prep_kernel(
    const float* __restrict__ w1, bf16_t* __restrict__ w1t,
    const int* __restrict__ idh, const int* __restrict__ idr,
    int* __restrict__ starts)
{
    if (blockIdx.x < 192) {
        int kc = blockIdx.x >> 3;        // 0..23
        int kg = blockIdx.x & 7;         // 0..7
        int n  = threadIdx.x;            // 0..255
        bf16x8 v;
        #pragma unroll
        for (int j = 0; j < 8; j++)
            v[j] = (bf16_t)w1[(size_t)(kc * 64 + kg * 8 + j) * HID + n];
        *(bf16x8*)(w1t + (size_t)kc * (HID * BK) + n * BK + kg * 8) = v;
    } else {
        int blk = blockIdx.x - 192;      // 0..127 = 2 tensors x 64 batches
        int t = blk >> 6;
        int b = blk & 63;
        const int* ids = (t ? idr : idh) + b * SEQ;
        int w = threadIdx.x;
        int lo = 0, hi = SEQ;
        while (lo < hi) {
            int m = (lo + hi) >> 1;
            if (ids[m] < w) lo = m + 1; else hi = m;
        }
        int* row = starts + blk * 257;
        row[w] = lo;
        if (w == 0) row[256] = SEQ;
    }
}

// ---------------------------------------------------------------------------
// Kernel 2: segment-mean align — THREAD-LEVEL GATHER (max-TLP version).
//
// R2 post-mortem: three structurally different wave-level variants (register
// gather, register streaming, LDS-DMA streaming) all landed at 88-98 us /
// ~1.5 TB/s.  The invariant across them: <= 8192 total waves, each running a
// long latency-serialized task (~1 B/cyc/wave effective).  The known-good
// 6.3 TB/s pattern on this chip (m13 copy) is the opposite shape: a huge
// grid of tiny independent threads.  So: one THREAD per output f32x4 cell.
//   threads = 64 b x 2 t x 256 w x 192 chunks = 6.29M -> 98304 waves.
//   Each thread: n = st[w+1]-st[w] (~2) independent f32x4 row reads,
//   mean, bf16x4 store.  No LDS, no inline asm, no cross-lane ops, ~30 VGPR.
// Every input byte read exactly once; every wave is w-uniform automatically
// (192 = 3*64), so starts reads scalarize and the n-loop is non-divergent.
// ---------------------------------------------------------------------------
__global__ __launch_bounds__(256) void align_kernel(
    const float* __restrict__ hh, const float* __restrict__ hr,
    const int* __restrict__ starts, bf16_t* __restrict__ X)
{
    int idx  = blockIdx.x * 256 + threadIdx.x;     // 0 .. 6291455
    int rest = idx / 192;                          // (b,t,w) — wave-uniform
    int c    = idx - rest * 192;                   // f32x4 chunk within row
    rest     = __builtin_amdgcn_readfirstlane(rest);
    int w    = rest & 255;
    int t    = (rest >> 8) & 1;
    int b    = rest >> 9;

    const int* st = starts + (t * 64 + b) * 257;
    int lo = st[w];
    int hi = st[w + 1];

    const f32x4* src = (const f32x4*)((t ? hr : hh) + (size_t)b * SEQ * DIM);
    bf16_t*      dst = X + (size_t)b * NW * KDIM + (size_t)w * KDIM
                         + t * DIM + c * 4;

    bf16x4 o = {};
    int n = hi - lo;
    if (n > 0) {
        f32x4 acc = src[(size_t)lo * 192 + c];
        for (int s = lo + 1; s < hi; s++) {
            f32x4 v = src[(size_t)s * 192 + c];
            acc[0] += v[0]; acc[1] += v[1];
            acc[2] += v[2]; acc[3] += v[3];
        }
        float inv = 1.0f / (float)n;
        o[0] = (bf16_t)(acc[0] * inv);
        o[1] = (bf16_t)(acc[1] * inv);
        o[2] = (bf16_t)(acc[2] * inv);
        o[3] = (bf16_t)(acc[3] * inv);
    }
    *(bf16x4*)dst = o;
}

// ---------------------------------------------------------------------------
// Kernel 3: router GEMM (bf16 MFMA) via LDS -> alpha.  (unchanged)
// ---------------------------------------------------------------------------
__global__ __launch_bounds__(256) void gemm_alpha_kernel(
    const bf16_t* __restrict__ X, const bf16_t* __restrict__ w1t,
    const float* __restrict__ b1, const float* __restrict__ w2,
    const float* __restrict__ b2, float* __restrict__ out)
{
    __shared__ __align__(16) bf16_t Xs[BM][BKP];
    __shared__ __align__(16) bf16_t Ws[HID][BKP];
    __shared__ float alpha_acc[BM];

    int tid   = threadIdx.x;
    int lane  = tid & 63;
    int wv    = tid >> 6;
    int row16 = lane & 15;
    int quad  = lane >> 4;
    int tok0  = blockIdx.x * BM;

    f32x4 acc[2][4];
    #pragma unroll
    for (int mi = 0; mi < 2; mi++)
        #pragma unroll
        for (int ni = 0; ni < 4; ni++)
            acc[mi][ni] = (f32x4){0.f, 0.f, 0.f, 0.f};

    int xr = tid >> 3;
    int xc = tid & 7;

    for (int kc = 0; kc < NKT; kc++) {
        {
            const uint4* src = (const uint4*)(X + (size_t)(tok0 + xr) * KDIM + kc * BK + xc * 8);
            *(uint4*)(&Xs[xr][xc * 8]) = *src;
        }
        {
            const uint4* srcb = (const uint4*)(w1t + (size_t)kc * (HID * BK));
            #pragma unroll
            for (int i = 0; i < 8; i++) {
                int cidx = tid + i * 256;
                *(uint4*)(&Ws[cidx >> 3][(cidx & 7) * 8]) = srcb[cidx];
            }
        }
        __syncthreads();
        #pragma unroll
        for (int kk2 = 0; kk2 < 2; kk2++) {
            bf16x8 af[2], bfg[4];
            #pragma unroll
            for (int mi = 0; mi < 2; mi++)
                af[mi] = *(const bf16x8*)(&Xs[mi * 16 + row16][kk2 * 32 + quad * 8]);
            #pragma unroll
            for (int ni = 0; ni < 4; ni++)
                bfg[ni] = *(const bf16x8*)(&Ws[wv * 64 + ni * 16 + row16][kk2 * 32 + quad * 8]);
            #pragma unroll
            for (int mi = 0; mi < 2; mi++)
                #pragma unroll
                for (int ni = 0; ni < 4; ni++)
                    acc[mi][ni] = __builtin_amdgcn_mfma_f32_16x16x32_bf16(
                        af[mi], bfg[ni], acc[mi][ni], 0, 0, 0);
        }
        __syncthreads();
    }

    float w2v[4], b1v[4];
    #pragma unroll
    for (int ni = 0; ni < 4; ni++) {
        int col = wv * 64 + ni * 16 + row16;
        w2v[ni] = w2[col];
        b1v[ni] = b1[col];
    }
    if (tid < BM) alpha_acc[tid] = 0.f;
    __syncthreads();

    #pragma unroll
    for (int mi = 0; mi < 2; mi++) {
        #pragma unroll
        for (int r = 0; r < 4; r++) {
            float p = 0.f;
            #pragma unroll
            for (int ni = 0; ni < 4; ni++) {
                float v = acc[mi][ni][r] + b1v[ni];
                v = v > 0.f ? v : 0.f;
                p += v * w2v[ni];
            }
            p += __shfl_xor(p, 1);
            p += __shfl_xor(p, 2);
            p += __shfl_xor(p, 4);
            p += __shfl_xor(p, 8);
            if (row16 == 0)
                atomicAdd(&alpha_acc[mi * 16 + quad * 4 + r], p);
        }
    }
    __syncthreads();
    if (tid < BM) {
        float a = 1.f / (1.f + expf(-(alpha_acc[tid] + b2[0])));
        out[(size_t)NT * NL + tok0 + tid] = a;
    }
}

// ---------------------------------------------------------------------------
// Kernel 4: blend + head + l2. 8 tokens per wave. Grid 512. (unchanged)
// ---------------------------------------------------------------------------
__global__ __launch_bounds__(256) void blend_kernel(
    const bf16_t* __restrict__ X, const float* __restrict__ hw,
    const float* __restrict__ hb, float* __restrict__ out)
{
    __shared__ float hws[NL * DIM];       // [l][d]
    int tid  = threadIdx.x;
    int lane = tid & 63;
    int wv   = tid >> 6;

    for (int i = tid; i < DIM * NL; i += 256) {
        int d = i / NL, l = i - d * NL;
        hws[l * DIM + d] = hw[i];
    }
    __syncthreads();

    int g   = lane >> 3;
    int u   = lane & 7;
    int tok = blockIdx.x * 32 + wv * 8 + g;

    float a = out[(size_t)NT * NL + tok];
    const bf16_t* xrow = X + (size_t)tok * KDIM;

    float lg[NL] = {0.f, 0.f, 0.f, 0.f, 0.f, 0.f, 0.f};
    float l2 = 0.f;

    #pragma unroll
    for (int k = 0; k < 12; k++) {
        int d0 = (k * 8 + u) * 8;
        bf16x8 hp = *(const bf16x8*)(xrow + d0);
        bf16x8 rp = *(const bf16x8*)(xrow + DIM + d0);
        float bl[8];
        #pragma unroll
        for (int e = 0; e < 8; e++) {
            float hhv = (float)hp[e];
            float hrv = (float)rp[e];
            float df  = hhv - hrv;
            bl[e] = fmaf(a, df, hrv);
            l2 = fmaf(df, df, l2);
        }
        #pragma unroll
        for (int l = 0; l < NL; l++) {
            f32x4 wA = *(const f32x4*)(&hws[l * DIM + d0]);
            f32x4 wB = *(const f32x4*)(&hws[l * DIM + d0 + 4]);
            lg[l] += bl[0]*wA[0] + bl[1]*wA[1] + bl[2]*wA[2] + bl[3]*wA[3]
                   + bl[4]*wB[0] + bl[5]*wB[1] + bl[6]*wB[2] + bl[7]*wB[3];
        }
    }

    #pragma unroll
    for (int off = 1; off < 8; off <<= 1) {
        #pragma unroll
        for (int l = 0; l < NL; l++) lg[l] += __shfl_xor(lg[l], off);
        l2 += __shfl_xor(l2, off);
    }

    if (u < NL) {
        float v = (u == 0) ? lg[0] : (u == 1) ? lg[1] : (u == 2) ? lg[2]
                : (u == 3) ? lg[3] : (u == 4) ? lg[4] : (u == 5) ? lg[5] : lg[6];
        out[(size_t)tok * NL + u] = v + hb[u];
    } else {
        out[(size_t)NT * NL + NT + tok] = sqrtf(l2);
    }
}

// ---------------------------------------------------------------------------
extern "C" void kernel_launch(void* const* d_in, const int* in_sizes, int n_in,
                              void* d_out, int out_size, void* d_ws, size_t ws_size,
                              hipStream_t stream)
{
    const float* hh  = (const float*)d_in[0];
    const float* hr  = (const float*)d_in[1];
    const int*   idh = (const int*)d_in[2];
    const int*   idr = (const int*)d_in[3];
    const float* w1  = (const float*)d_in[5];
    const float* b1  = (const float*)d_in[6];
    const float* w2  = (const float*)d_in[7];
    const float* b2  = (const float*)d_in[8];
    const float* hw  = (const float*)d_in[9];
    const float* hb  = (const float*)d_in[10];
    float* out = (float*)d_out;

    bf16_t* X      = (bf16_t*)d_ws;                        // 50.33 MB
    bf16_t* w1t    = X + (size_t)NT * KDIM;                // 0.79 MB (tiled)
    int*    starts = (int*)(w1t + (size_t)NKT * HID * BK); // 263 KB

    prep_kernel<<<320, 256, 0, stream>>>(w1, w1t, idh, idr, starts);
    align_kernel<<<24576, 256, 0, stream>>>(hh, hr, starts, X);
    gemm_alpha_kernel<<<NT / BM, 256, 0, stream>>>(X, w1t, b1, w2, b2, out);
    blend_kernel<<<512, 256, 0, stream>>>(X, hw, hb, out);
}